// Round 9
// baseline (46631.711 us; speedup 1.0000x reference)
//
#include <hip/hip_runtime.h>
#include <stdint.h>

#define HID 1024
#define NGATE 4096
#define BATCH 256
#define TENC 128
#define VOCAB 1024
#define NOUT 125
#define TDEC (16 + NOUT)   // 141
#define MAXTHINK 16
#define STOPCLS 1023
#define CH 8

typedef __attribute__((ext_vector_type(8))) short short8;
typedef __attribute__((ext_vector_type(4))) float f32x4;

#define H3PL 262144                  // h3/cur3 plane stride (elems)
#define WPLE ((size_t)NGATE*1024)    // wih/whh plane stride (elems)
#define VPLE ((size_t)VOCAB*1024)    // wfc plane stride (elems)
#define MFMA_B __builtin_amdgcn_mfma_f32_16x16x32_bf16

// ---------------- threefry2x32 (exact JAX partitionable semantics) ----------------
__device__ __forceinline__ uint32_t rotl32(uint32_t v, int r){ return (v<<r)|(v>>(32-r)); }

__device__ __forceinline__ void tf2x32(uint32_t k0, uint32_t k1, uint32_t x0, uint32_t x1,
                                       uint32_t& o0, uint32_t& o1)
{
  uint32_t k2 = k0 ^ k1 ^ 0x1BD11BDAu;
  x0 += k0; x1 += k1;
#define R4(a,b,cc,d) x0+=x1;x1=rotl32(x1,a);x1^=x0; x0+=x1;x1=rotl32(x1,b);x1^=x0; \
                     x0+=x1;x1=rotl32(x1,cc);x1^=x0; x0+=x1;x1=rotl32(x1,d);x1^=x0;
  R4(13,15,26,6)  x0+=k1; x1+=k2+1u;
  R4(17,29,16,24) x0+=k2; x1+=k0+2u;
  R4(13,15,26,6)  x0+=k0; x1+=k1+3u;
  R4(17,29,16,24) x0+=k1; x1+=k2+4u;
  R4(13,15,26,6)  x0+=k2; x1+=k0+5u;
#undef R4
  o0 = x0; o1 = x1;
}

__device__ __forceinline__ uint32_t jax_bits(uint32_t fk0, uint32_t fk1, uint32_t i)
{
  uint32_t o0, o1;
  tf2x32(fk0, fk1, 0u, i, o0, o1);   // 64-bit iota: hi=0, lo=i
  return o0 ^ o1;                     // XOR-fold (jax_threefry_partitionable)
}

__device__ __forceinline__ float sigm(float x){ return 0.5f + 0.5f*tanhf(0.5f*x); }

__device__ __forceinline__ ushort bf16rn(float v){
  uint32_t u = __float_as_uint(v);
  uint32_t r = (u + 0x7fffu + ((u>>16)&1u)) >> 16;
  return (ushort)r;
}
__device__ __forceinline__ float bf16tof(ushort s){ return __uint_as_float(((uint32_t)s)<<16); }

typedef ushort LdsAS[2][3][64][40];

// ---------------- distributed grid barrier (no RMW contention) ----------------
// flags[bid*16]: per-block arrival slot (64B apart). Block 0 polls all in parallel,
// then releases gen. Other blocks acquire-spin on gen. Epoch increments per barrier;
// prep re-zeros flags/gen each call.
__device__ __forceinline__ void gbar(int* flags, int* gen, int e, int bid, int tid)
{
  __syncthreads();
  if (tid == 0)
    __hip_atomic_store(&flags[bid*16], e, __ATOMIC_RELEASE, __HIP_MEMORY_SCOPE_AGENT);
  if (bid == 0){
    while (__hip_atomic_load(&flags[tid*16], __ATOMIC_ACQUIRE, __HIP_MEMORY_SCOPE_AGENT) < e)
      __builtin_amdgcn_s_sleep(1);
    __syncthreads();
    if (tid == 0)
      __hip_atomic_store(gen, e, __ATOMIC_RELEASE, __HIP_MEMORY_SCOPE_AGENT);
  } else {
    if (tid == 0){
      while (__hip_atomic_load(gen, __ATOMIC_ACQUIRE, __HIP_MEMORY_SCOPE_AGENT) < e)
        __builtin_amdgcn_s_sleep(1);
    }
  }
  __threadfence();   // acquire-side: invalidate so whole CU sees cross-XCD writes
  __syncthreads();
}

// ---------------- prep ----------------
__global__ __launch_bounds__(256) void prep_kernel(
    const float* __restrict__ b_ih, const float* __restrict__ b_hh,
    const float* __restrict__ x, const int* __restrict__ lengths,
    float* __restrict__ bsum, int* __restrict__ ints,
    ushort* __restrict__ h3, ushort* __restrict__ cur3)
{
  int idx = blockIdx.x*256 + threadIdx.x;           // 0 .. 262143
  if (idx < NGATE) bsum[idx] = b_ih[idx] + b_hh[idx];
  if (idx < BATCH){
    ints[idx] = 1; ints[512+idx] = 0; ints[768+idx] = 0;   // is_think, think_steps, out_steps
    ints[2048 + idx*16] = 0;                               // barrier flags
  }
  if (idx == 0) ints[6400] = 0;                            // barrier gen
  #pragma unroll
  for (int p=0;p<3;p++) h3[p*H3PL + idx] = 0;
  int b = idx >> 10, k = idx & (HID-1);
  int L = lengths[b];
  float v = x[((size_t)b*TENC + (size_t)(L-1))*HID + k];
  #pragma unroll
  for (int p=0;p<3;p++){ ushort pp = bf16rn(v); v -= bf16tof(pp); cur3[p*H3PL + idx] = pp; }
}

// ---------------- weight pre-split into frag-ordered bf16 planes ----------------
__global__ __launch_bounds__(256) void splitw_kernel(
    const float* __restrict__ W, ushort* __restrict__ Wf, int N)
{
  int idx = blockIdx.x*256 + threadIdx.x;   // n*128 + kc
  int n = idx >> 7, kc = idx & 127;
  float v[8];
  *(float4*)&v[0] = *(const float4*)(W + (size_t)n*1024 + kc*8);
  *(float4*)&v[4] = *(const float4*)(W + (size_t)n*1024 + kc*8 + 4);
  size_t base = ((size_t)(n>>4)*128 + kc)*128 + (n&15)*8;
  #pragma unroll
  for (int p=0;p<3;p++){
    ushort o[8];
    #pragma unroll
    for (int e=0;e<8;e++){ ushort pp = bf16rn(v[e]); v[e] -= bf16tof(pp); o[e] = pp; }
    *(uint4*)(Wf + (size_t)p*N*1024 + base) = *(uint4*)o;
  }
}

// ================= device phase helpers =================

// gates + LSTM cell. MODE0: encoder (K=1024 h·Whh + xg, mask). MODE1: decode K=2048
// ([cur3|h3]·[Wih|Whh]). MODE2: decode K=1024 h·Whh + f32 W_ih column gather (one-hot cur).
template<int PL, int MODE>
__device__ void gates_do(
    const ushort* __restrict__ A0, const ushort* __restrict__ A1,
    const ushort* __restrict__ Wih, const ushort* __restrict__ Whh,
    const float* __restrict__ xg_t, const float* __restrict__ Wihf,
    const int* __restrict__ pred, const int* len4, int t,
    float* creg, ushort* __restrict__ h3new, LdsAS& As,
    int b0, int jg, int fr, int q, int arow, int ach, int w,
    float bi, float bf_, float bg, float bo)
{
  constexpr int KT = (MODE==1) ? 64 : 32;
  f32x4 acc[4] = {};

#define LOADSA(sv, kc) { \
  const ushort* asel = (MODE==1) ? (((kc) < 32) ? A0 : A1) : A0; \
  int kl = (kc) & 31; \
  _Pragma("unroll") for (int p=0;p<PL;p++) \
    sv[p] = *(const uint4*)(asel + (size_t)p*H3PL + (size_t)(b0+arow)*1024 + kl*32 + ach*8); }

#define LOADB(dst, kc) { \
  const ushort* wsel = (MODE==1) ? (((kc) < 32) ? Wih : Whh) : Whh; \
  int kl = (kc) & 31; \
  _Pragma("unroll") for (int p=0;p<PL;p++) \
  _Pragma("unroll") for (int gg=0; gg<4; gg++) \
    dst[p][gg] = *(const short8*)(wsel + (size_t)p*WPLE + ((size_t)(jg + gg*64)*128 + kl*4 + q)*128 + fr*8); }

#define STAGE(buf, sv) { _Pragma("unroll") for (int p=0;p<PL;p++) *(uint4*)&As[buf][p][arow][ach*8] = sv[p]; }

#define READA(af, buf) { _Pragma("unroll") for (int p=0;p<PL;p++) af[p] = *(const short8*)&As[buf][p][w*16 + fr][q*8]; }

#define DOMFMA(af, bf) { _Pragma("unroll") for (int gg=0; gg<4; gg++){ \
  if constexpr (PL==3){ \
    acc[gg] = MFMA_B(af[2], bf[0][gg], acc[gg], 0,0,0); \
    acc[gg] = MFMA_B(af[1], bf[1][gg], acc[gg], 0,0,0); \
    acc[gg] = MFMA_B(af[0], bf[2][gg], acc[gg], 0,0,0); \
    acc[gg] = MFMA_B(af[1], bf[0][gg], acc[gg], 0,0,0); \
    acc[gg] = MFMA_B(af[0], bf[1][gg], acc[gg], 0,0,0); \
    acc[gg] = MFMA_B(af[0], bf[0][gg], acc[gg], 0,0,0); \
  } else { \
    acc[gg] = MFMA_B(af[0], bf[0][gg], acc[gg], 0,0,0); \
  } } }

  uint4 svA[PL];
  short8 bcur[PL][4], bnxt[PL][4], af[PL];
  LOADSA(svA, 0); LOADB(bcur, 0);
  for (int kc = 0; kc < KT; kc += 2){
    STAGE(0, svA);
    __syncthreads();
    LOADSA(svA, kc+1);
    LOADB(bnxt, kc+1);
    READA(af, 0);
    DOMFMA(af, bcur);
    STAGE(1, svA);
    __syncthreads();
    if (kc+2 < KT){ LOADSA(svA, kc+2); LOADB(bcur, kc+2); }
    READA(af, 1);
    DOMFMA(af, bnxt);
  }
#undef LOADSA
#undef LOADB
#undef STAGE
#undef READA
#undef DOMFMA

  int k = jg*16 + fr;
  #pragma unroll
  for (int r=0;r<4;r++){
    int b = b0 + w*16 + q*4 + r;
    int cidx = b*1024 + k;
    if (MODE==0 && t >= len4[r]){
      #pragma unroll
      for (int p=0;p<PL;p++) h3new[p*H3PL + cidx] = A0[p*H3PL + cidx];   // keep old h,c
      continue;
    }
    float gi = acc[0][r], gf = acc[1][r], gg2 = acc[2][r], go = acc[3][r];
    if (MODE==0){
      gi  += xg_t[(size_t)b*NGATE + k       ];
      gf  += xg_t[(size_t)b*NGATE + k + 1024];
      gg2 += xg_t[(size_t)b*NGATE + k + 2048];
      go  += xg_t[(size_t)b*NGATE + k + 3072];
    }
    if (MODE==2){
      int pp = pred[b];
      gi  += Wihf[(size_t)(k       )*HID + pp];
      gf  += Wihf[(size_t)(k + 1024)*HID + pp];
      gg2 += Wihf[(size_t)(k + 2048)*HID + pp];
      go  += Wihf[(size_t)(k + 3072)*HID + pp];
    }
    gi += bi; gf += bf_; gg2 += bg; go += bo;
    float cn = sigm(gf)*creg[r] + sigm(gi)*tanhf(gg2);
    float hn = sigm(go)*tanhf(cn);
    creg[r] = cn;
    float v = hn;
    #pragma unroll
    for (int p=0;p<PL;p++){ ushort pp = bf16rn(v); v -= bf16tof(pp); h3new[p*H3PL + cidx] = pp; }
  }
}

// encoder chunk x-GEMM tile (M=2048 rows of xs3, N=4096, K=1024)
template<int PL>
__device__ void xgemm_do(const ushort* __restrict__ A, const ushort* __restrict__ Wf,
                         float* __restrict__ C, int tile, LdsAS& As, int tid)
{
  int xcd = tile & 7, s = tile >> 3;
  int b = s & 31;              // Mtiles = 32
  int G = (s >> 5)*8 + xcd;    // Ntiles = 64
  int j0 = G << 6, b0 = b << 6;
  int lane = tid & 63, w = tid >> 6;
  int mb = (w >> 1) << 5, nb = (w & 1) << 5;
  int fr = lane & 15, q = lane >> 4;
  int arow = tid >> 2, aq = tid & 3;

  __syncthreads();   // protect LDS reuse across sequential tiles

  const ushort* Ap = A + (size_t)(b0 + arow)*1024 + aq*8;
  const size_t aps = (size_t)CH*BATCH*1024;
  uint4 sv[PL];
  #pragma unroll
  for (int p=0;p<PL;p++) sv[p] = *(const uint4*)(Ap + p*aps);

  const ushort* wbase[PL][2];
  #pragma unroll
  for (int p=0;p<PL;p++)
    #pragma unroll
    for (int f=0;f<2;f++)
      wbase[p][f] = Wf + (size_t)p*WPLE + ((size_t)(((j0+nb)>>4) + f)*128 + q)*128 + fr*8;

  f32x4 acc[2][2] = {};
  int cb = 0;
  for (int kc0 = 0; kc0 < 128; kc0 += 4){
    #pragma unroll
    for (int p=0;p<PL;p++) *(uint4*)&As[cb][p][arow][aq*8] = sv[p];
    __syncthreads();
    if (kc0 + 4 < 128){
      #pragma unroll
      for (int p=0;p<PL;p++) sv[p] = *(const uint4*)(Ap + p*aps + (kc0+4)*8);
    }
    short8 afr[PL][2], bfr[PL][2];
    #pragma unroll
    for (int p=0;p<PL;p++)
      #pragma unroll
      for (int f=0;f<2;f++){
        bfr[p][f] = *(const short8*)(wbase[p][f] + (size_t)kc0*128);
        afr[p][f] = *(const short8*)&As[cb][p][mb + f*16 + fr][q*8];
      }
    #pragma unroll
    for (int f=0;f<2;f++)
      #pragma unroll
      for (int g=0;g<2;g++){
        if constexpr (PL==3){
          acc[f][g] = MFMA_B(afr[2][f], bfr[0][g], acc[f][g], 0,0,0);
          acc[f][g] = MFMA_B(afr[1][f], bfr[1][g], acc[f][g], 0,0,0);
          acc[f][g] = MFMA_B(afr[0][f], bfr[2][g], acc[f][g], 0,0,0);
          acc[f][g] = MFMA_B(afr[1][f], bfr[0][g], acc[f][g], 0,0,0);
          acc[f][g] = MFMA_B(afr[0][f], bfr[1][g], acc[f][g], 0,0,0);
          acc[f][g] = MFMA_B(afr[0][f], bfr[0][g], acc[f][g], 0,0,0);
        } else {
          acc[f][g] = MFMA_B(afr[0][f], bfr[0][g], acc[f][g], 0,0,0);
        }
      }
    cb ^= 1;
  }
  int crow = q*4, ccol = fr;
  #pragma unroll
  for (int f=0;f<2;f++)
    #pragma unroll
    for (int g=0;g<2;g++)
      #pragma unroll
      for (int r=0;r<4;r++)
        C[(size_t)(b0 + mb + f*16 + crow + r)*NGATE + (j0 + nb + g*16 + ccol)] = acc[f][g][r];
}

// FC: logits[0:256][0:1024] = h3 · wfc^T. 32x32 tiles, 256 blocks.
template<int PL>
__device__ void fc_do(const ushort* __restrict__ h3, const ushort* __restrict__ wfc,
                      float* __restrict__ logits, int bid, int tid)
{
  int lane = tid & 63, w = tid >> 6;
  int mt = bid >> 5, nt = bid & 31;
  int m0 = mt << 5, n0 = nt << 5;
  int wr = (w >> 1) << 4, wc = (w & 1) << 4;
  int fr = lane & 15, q = lane >> 4;
  const ushort* ap = h3 + (size_t)(m0 + wr + fr)*1024 + q*8;
  const ushort* bp = wfc + ((size_t)((n0 + wc) >> 4)*128 + q)*128 + fr*8;
  f32x4 acc = {};
  short8 a0[PL], b0v[PL], a1[PL], b1v[PL];
  #pragma unroll
  for (int p=0;p<PL;p++){ a0[p] = *(const short8*)(ap + p*H3PL); b0v[p] = *(const short8*)(bp + p*VPLE); }
  for (int s2 = 0; s2 < 32; s2++){
    if (s2 < 31){
      #pragma unroll
      for (int p=0;p<PL;p++){
        a1[p]  = *(const short8*)(ap + (size_t)p*H3PL + (s2+1)*32);
        b1v[p] = *(const short8*)(bp + (size_t)p*VPLE + (size_t)(s2+1)*4*128);
      }
    }
    if constexpr (PL==3){
      acc = MFMA_B(a0[2], b0v[0], acc, 0,0,0);
      acc = MFMA_B(a0[1], b0v[1], acc, 0,0,0);
      acc = MFMA_B(a0[0], b0v[2], acc, 0,0,0);
      acc = MFMA_B(a0[1], b0v[0], acc, 0,0,0);
      acc = MFMA_B(a0[0], b0v[1], acc, 0,0,0);
      acc = MFMA_B(a0[0], b0v[0], acc, 0,0,0);
    } else {
      acc = MFMA_B(a0[0], b0v[0], acc, 0,0,0);
    }
    #pragma unroll
    for (int p=0;p<PL;p++){ a0[p] = a1[p]; b0v[p] = b1v[p]; }
  }
  #pragma unroll
  for (int r=0;r<4;r++)
    logits[(size_t)(m0 + wr + q*4 + r)*1024 + n0 + wc + fr] = acc[r];
}

// decide: gumbel+argmax, state update, fo write, cur3 write
__device__ void decide_do(const float* __restrict__ logits, const float* __restrict__ b_fc, int t,
    const int* __restrict__ is_old, int* __restrict__ is_new,
    int* __restrict__ think_steps, int* __restrict__ out_steps, int* __restrict__ pred_out,
    float* __restrict__ out, ushort* __restrict__ cur3,
    float* s_red, int* s_idx, int* s_misc, int b, int tid)
{
  uint32_t fk0, fk1; tf2x32(0u, 42u, 0u, (uint32_t)t, fk0, fk1);
  float lg[4];
  float zb = -3.4e38f; int ib = 0;
  #pragma unroll
  for (int q2=0;q2<4;q2++){
    int v = tid + (q2<<8);
    uint32_t bits = jax_bits(fk0, fk1, (uint32_t)(b*VOCAB + v));
    float f = __uint_as_float((bits>>9) | 0x3F800000u) - 1.0f;
    const float TINY = 1.17549435e-38f;
    float u = fmaxf(TINY, f + TINY);
    float g = -logf(-logf(u));
    float l = logits[(size_t)b*VOCAB + v] + b_fc[v];
    lg[q2] = l;
    float zz = l + g;
    if (zz > zb){ zb = zz; ib = v; }
  }
  s_red[tid] = zb; s_idx[tid] = ib;
  if (tid==0) s_misc[0] = 0;
  __syncthreads();
  if (is_old[tid]) atomicOr(&s_misc[0], 1);      // any() over PRE-update snapshot
  __syncthreads();
  for (int s2=128;s2>0;s2>>=1){
    if (tid < s2){
      float om = s_red[tid+s2]; int oi = s_idx[tid+s2];
      if (om > s_red[tid] || (om==s_red[tid] && oi < s_idx[tid])){ s_red[tid]=om; s_idx[tid]=oi; }
    }
    __syncthreads();
  }
  if (tid==0){
    int pred = s_idx[0]; s_misc[1] = pred;
    pred_out[b] = pred;
    int isth = is_old[b];
    int os = out_steps[b];
    int outp = (!isth && os < NOUT) ? 1 : 0;
    s_misc[2] = outp;
    s_misc[3] = os < (NOUT-1) ? os : (NOUT-1);
    int nts = think_steps[b] + (isth ? 1 : 0);
    out_steps[b] = os + outp;
    think_steps[b] = nts;
    int jf = (isth && ((pred==STOPCLS) || (nts >= MAXTHINK))) ? 1 : 0;
    is_new[b] = (isth && !jf) ? 1 : 0;
    if (t == TDEC-1) out[(size_t)BATCH*NOUT*(VOCAB-1) + b] = (float)nts;
  }
  __syncthreads();
  int any = s_misc[0], pred = s_misc[1], outp = s_misc[2], si = s_misc[3];
  #pragma unroll
  for (int q2=0;q2<4;q2++){
    int v = tid + (q2<<8);
    float l = lg[q2];
    float cv = any ? l : (v==pred ? 1.0f : 0.0f);
    float t2 = cv;
    #pragma unroll
    for (int p=0;p<3;p++){ ushort pp = bf16rn(t2); t2 -= bf16tof(pp); cur3[p*H3PL + b*1024 + v] = pp; }
    if (outp && v < (VOCAB-1))
      out[((size_t)b*NOUT + si)*(VOCAB-1) + v] = l;
  }
}

// ================= persistent kernel (normal launch, distributed grid barrier) =================
struct KP {
  const float *x, *W_ih, *b_fc;
  const int *lengths;
  const float *bsum;
  float *logits, *out, *xg;
  ushort *h3a, *h3b, *cur3, *wih3, *whh3, *wfc3, *xs3;
  int *ints;
};

__global__ __launch_bounds__(256, 1) void persist(KP P)
{
  __shared__ LdsAS As;
  __shared__ float s_red[256];
  __shared__ int s_idx[256];
  __shared__ int s_misc[8];

  int bid = blockIdx.x, tid = threadIdx.x;
  int lane = tid & 63, w = tid >> 6;
  int fr = lane & 15, q = lane >> 4;
  int arow = tid >> 2, ach = tid & 3;
  int xcd = bid & 7, sb = bid >> 3;
  int b0 = (sb & 3) << 6;
  int jg = (sb >> 2)*8 + xcd;
  int gk = jg*16 + fr;
  float bi = P.bsum[gk], bf_ = P.bsum[gk+1024], bg = P.bsum[gk+2048], bo = P.bsum[gk+3072];
  int len4[4];
  float creg[4] = {0.f,0.f,0.f,0.f};
  #pragma unroll
  for (int r=0;r<4;r++) len4[r] = P.lengths[b0 + w*16 + q*4 + r];

  int* is_think    = P.ints;
  int* think_steps = P.ints + 512;
  int* out_steps   = P.ints + 768;
  int* pred        = P.ints + 1024;
  int* bflags      = P.ints + 2048;
  int* bgen        = P.ints + 6400;
  int epoch = 0;
  ushort* h3[2] = { P.h3a, P.h3b };
  int hc = 0;

#define GBAR() gbar(bflags, bgen, ++epoch, bid, tid)

  // ---- encoder ----
  for (int tc = 0; tc < TENC/CH; ++tc){
    { // xsplit phase
      int gt = bid*256 + tid;
      #pragma unroll
      for (int i=0;i<8;i++){
        int idx4 = gt + i*65536;
        int row = idx4 >> 8; int k4 = (idx4 & 255) << 2;
        int b = row & 255, jj = row >> 8;
        float v[4];
        *(float4*)v = *(const float4*)(P.x + ((size_t)b*TENC + tc*CH + jj)*HID + k4);
        #pragma unroll
        for (int p=0;p<3;p++){
          ushort o[4];
          #pragma unroll
          for (int e=0;e<4;e++){ ushort pp = bf16rn(v[e]); v[e] -= bf16tof(pp); o[e] = pp; }
          *(uint2*)(P.xs3 + (size_t)p*CH*BATCH*1024 + (size_t)row*1024 + k4) = *(uint2*)o;
        }
      }
    }
    GBAR();
    for (int i=0;i<8;i++)
      xgemm_do<3>(P.xs3, P.wih3, P.xg, bid + i*256, As, tid);
    GBAR();
    for (int tt=0;tt<CH;tt++){
      int t = tc*CH + tt;
      gates_do<3,0>(h3[hc], nullptr, nullptr, P.whh3, P.xg + (size_t)tt*BATCH*NGATE,
                    nullptr, nullptr, len4, t, creg, h3[hc^1], As,
                    b0, jg, fr, q, arow, ach, w, bi, bf_, bg, bo);
      hc ^= 1;
      GBAR();
    }
  }

  // ---- decode ----
  for (int t = 0; t < TDEC; ++t){
    if (t < MAXTHINK)
      gates_do<3,1>(P.cur3, h3[hc], P.wih3, P.whh3, nullptr, nullptr, nullptr,
                    len4, t, creg, h3[hc^1], As, b0, jg, fr, q, arow, ach, w, bi, bf_, bg, bo);
    else if (t == MAXTHINK)   // cur is still LOGITS here (any(is_think) was true at t=15)
      gates_do<1,1>(P.cur3, h3[hc], P.wih3, P.whh3, nullptr, nullptr, nullptr,
                    len4, t, creg, h3[hc^1], As, b0, jg, fr, q, arow, ach, w, bi, bf_, bg, bo);
    else                      // t>=17: cur is exactly one-hot(pred) -> f32 W_ih column gather
      gates_do<1,2>(h3[hc], nullptr, nullptr, P.whh3, nullptr, P.W_ih, pred,
                    len4, t, creg, h3[hc^1], As, b0, jg, fr, q, arow, ach, w, bi, bf_, bg, bo);
    hc ^= 1;
    GBAR();
    if (t < MAXTHINK) fc_do<3>(h3[hc], P.wfc3, P.logits, bid, tid);
    else              fc_do<1>(h3[hc], P.wfc3, P.logits, bid, tid);
    GBAR();
    decide_do(P.logits, P.b_fc, t, is_think + (t&1)*BATCH, is_think + ((t+1)&1)*BATCH,
              think_steps, out_steps, pred, P.out, P.cur3, s_red, s_idx, s_misc, bid, tid);
    GBAR();
  }
#undef GBAR
}

// ---------------- host ----------------
extern "C" void kernel_launch(void* const* d_in, const int* in_sizes, int n_in,
                              void* d_out, int out_size, void* d_ws, size_t ws_size,
                              hipStream_t stream)
{
  const float* x    = (const float*)d_in[0];
  const float* W_ih = (const float*)d_in[1];
  const float* W_hh = (const float*)d_in[2];
  const float* b_ih = (const float*)d_in[3];
  const float* b_hh = (const float*)d_in[4];
  const float* W_fc = (const float*)d_in[5];
  const float* b_fc = (const float*)d_in[6];
  const int*   lengths = (const int*)d_in[7];
  float* out = (float*)d_out;
  char* W = (char*)d_ws;

  constexpr size_t OF_BSUM = 0;
  constexpr size_t OF_C    = OF_BSUM + 16384;       // (unused slot, keeps layout stable)
  constexpr size_t OF_LG   = OF_C    + 1048576;
  constexpr size_t OF_H3A  = OF_LG   + 1048576;
  constexpr size_t OF_H3B  = OF_H3A  + 1572864;
  constexpr size_t OF_CUR3 = OF_H3B  + 1572864;
  constexpr size_t OF_WIH  = OF_CUR3 + 1572864;
  constexpr size_t OF_WHH  = OF_WIH  + (size_t)3*NGATE*1024*2;
  constexpr size_t OF_WFC  = OF_WHH  + (size_t)3*NGATE*1024*2;
  constexpr size_t OF_INTS = OF_WFC  + (size_t)3*VOCAB*1024*2;

  float* bsum   = (float*)(W + OF_BSUM);
  float* logits = (float*)(W + OF_LG);
  ushort* h3a   = (ushort*)(W + OF_H3A);
  ushort* h3b   = (ushort*)(W + OF_H3B);
  ushort* cur3  = (ushort*)(W + OF_CUR3);
  ushort* wih3  = (ushort*)(W + OF_WIH);
  ushort* whh3  = (ushort*)(W + OF_WHH);
  ushort* wfc3  = (ushort*)(W + OF_WFC);
  int* ints = (int*)(W + OF_INTS);

  // encoder-only scratch aliased into d_out's fo region (fully rewritten in out-phase)
  float*  xg  = (float*)d_out;                                      // 32 MiB
  ushort* xs3 = (ushort*)((char*)d_out + (size_t)CH*BATCH*NGATE*4); // 12 MiB

  splitw_kernel<<<NGATE/2, 256, 0, stream>>>(W_ih, wih3, NGATE);
  splitw_kernel<<<NGATE/2, 256, 0, stream>>>(W_hh, whh3, NGATE);
  splitw_kernel<<<VOCAB/2, 256, 0, stream>>>(W_fc, wfc3, VOCAB);
  prep_kernel<<<1024, 256, 0, stream>>>(b_ih, b_hh, x, lengths, bsum, ints, h3a, cur3);

  KP P;
  P.x = x; P.W_ih = W_ih; P.b_fc = b_fc; P.lengths = lengths;
  P.bsum = bsum; P.logits = logits; P.out = out; P.xg = xg;
  P.h3a = h3a; P.h3b = h3b; P.cur3 = cur3;
  P.wih3 = wih3; P.whh3 = whh3; P.wfc3 = wfc3; P.xs3 = xs3;
  P.ints = ints;

  persist<<<dim3(256), dim3(256), 0, stream>>>(P);
}

// Round 10
// 17887.775 us; speedup vs baseline: 2.6069x; 2.6069x over previous
//
#include <hip/hip_runtime.h>
#include <stdint.h>

#define HID 1024
#define NGATE 4096
#define BATCH 256
#define TENC 128
#define VOCAB 1024
#define NOUT 125
#define TDEC 141
#define MAXTHINK 16
#define STOPCLS 1023

typedef __attribute__((ext_vector_type(8))) short short8;
typedef __attribute__((ext_vector_type(4))) float f32x4;

#define H3PL 262144                  // h3/cur3 plane stride (elems)
#define WPLE ((size_t)NGATE*1024)    // wih/whh plane stride (elems)
#define VPLE ((size_t)VOCAB*1024)    // wfc plane stride (elems)
#define MFMA_B __builtin_amdgcn_mfma_f32_16x16x32_bf16

// ints[] offsets (elements)
#define I_CLAIM 0       // 8
#define I_FLAGS 64      // 256*16
#define I_GEN   4224
#define I_ANY   4288    // 142
#define I_PRED  4608    // 256

// ---------------- threefry2x32 (exact JAX partitionable semantics) ----------------
__device__ __forceinline__ uint32_t rotl32(uint32_t v, int r){ return (v<<r)|(v>>(32-r)); }

__device__ __forceinline__ void tf2x32(uint32_t k0, uint32_t k1, uint32_t x0, uint32_t x1,
                                       uint32_t& o0, uint32_t& o1)
{
  uint32_t k2 = k0 ^ k1 ^ 0x1BD11BDAu;
  x0 += k0; x1 += k1;
#define R4(a,b,cc,d) x0+=x1;x1=rotl32(x1,a);x1^=x0; x0+=x1;x1=rotl32(x1,b);x1^=x0; \
                     x0+=x1;x1=rotl32(x1,cc);x1^=x0; x0+=x1;x1=rotl32(x1,d);x1^=x0;
  R4(13,15,26,6)  x0+=k1; x1+=k2+1u;
  R4(17,29,16,24) x0+=k2; x1+=k0+2u;
  R4(13,15,26,6)  x0+=k0; x1+=k1+3u;
  R4(17,29,16,24) x0+=k1; x1+=k2+4u;
  R4(13,15,26,6)  x0+=k2; x1+=k0+5u;
#undef R4
  o0 = x0; o1 = x1;
}

__device__ __forceinline__ uint32_t jax_bits(uint32_t fk0, uint32_t fk1, uint32_t i)
{
  uint32_t o0, o1;
  tf2x32(fk0, fk1, 0u, i, o0, o1);
  return o0 ^ o1;
}

__device__ __forceinline__ float sigm(float x){ return 0.5f + 0.5f*tanhf(0.5f*x); }

__device__ __forceinline__ ushort bf16rn(float v){
  uint32_t u = __float_as_uint(v);
  uint32_t r = (u + 0x7fffu + ((u>>16)&1u)) >> 16;
  return (ushort)r;
}
__device__ __forceinline__ float bf16tof(ushort s){ return __uint_as_float(((uint32_t)s)<<16); }

typedef ushort LdsAS[2][3][32][40];   // row stride 80B (16B-aligned for b128 reads)

// ---------------- grid barrier: control-only, L1-invalidate (L2 stays warm) ----------------
__device__ __forceinline__ void gbar(int* flags, int* gen, int e, int rk, int tid)
{
  __syncthreads();   // compiler drains vmcnt before s_barrier -> stores are in L2
  if (tid == 0)
    __hip_atomic_store(&flags[rk*16], e, __ATOMIC_RELAXED, __HIP_MEMORY_SCOPE_AGENT);
  if (rk == 0){
    while (__hip_atomic_load(&flags[tid*16], __ATOMIC_RELAXED, __HIP_MEMORY_SCOPE_AGENT) < e)
      __builtin_amdgcn_s_sleep(2);
    __syncthreads();
    if (tid == 0)
      __hip_atomic_store(gen, e, __ATOMIC_RELAXED, __HIP_MEMORY_SCOPE_AGENT);
  } else if (tid == 0){
    while (__hip_atomic_load(gen, __ATOMIC_RELAXED, __HIP_MEMORY_SCOPE_AGENT) < e)
      __builtin_amdgcn_s_sleep(2);
  }
  __syncthreads();
  asm volatile("buffer_inv sc0" ::: "memory");   // L1 only; weights stay L2-resident
}

// ---------------- prep ----------------
__global__ __launch_bounds__(256) void prep_kernel(
    const float* __restrict__ b_ih, const float* __restrict__ b_hh,
    const float* __restrict__ x, const int* __restrict__ lengths,
    float* __restrict__ bsum, int* __restrict__ ints,
    ushort* __restrict__ h3, ushort* __restrict__ cur3)
{
  int idx = blockIdx.x*256 + threadIdx.x;           // 0 .. 262143
  if (idx < NGATE) bsum[idx] = b_ih[idx] + b_hh[idx];
  if (idx < 8)   ints[I_CLAIM + idx] = 0;
  if (idx < 256) ints[I_FLAGS + idx*16] = 0;
  if (idx == 0)  ints[I_GEN] = 0;
  if (idx < TDEC+1) ints[I_ANY + idx] = (idx==0) ? 1 : 0;
  #pragma unroll
  for (int p=0;p<3;p++) h3[p*H3PL + idx] = 0;
  int b = idx >> 10, k = idx & (HID-1);
  int L = lengths[b];
  float v = x[((size_t)b*TENC + (size_t)(L-1))*HID + k];
  #pragma unroll
  for (int p=0;p<3;p++){ ushort pp = bf16rn(v); v -= bf16tof(pp); cur3[p*H3PL + idx] = pp; }
}

// ---------------- weight pre-split into frag-ordered bf16 planes ----------------
__global__ __launch_bounds__(256) void splitw_kernel(
    const float* __restrict__ W, ushort* __restrict__ Wf, int N)
{
  int idx = blockIdx.x*256 + threadIdx.x;   // n*128 + kc
  int n = idx >> 7, kc = idx & 127;
  float v[8];
  *(float4*)&v[0] = *(const float4*)(W + (size_t)n*1024 + kc*8);
  *(float4*)&v[4] = *(const float4*)(W + (size_t)n*1024 + kc*8 + 4);
  size_t base = ((size_t)(n>>4)*128 + kc)*128 + (n&15)*8;
  #pragma unroll
  for (int p=0;p<3;p++){
    ushort o[8];
    #pragma unroll
    for (int e=0;e<8;e++){ ushort pp = bf16rn(v[e]); v[e] -= bf16tof(pp); o[e] = pp; }
    *(uint4*)(Wf + (size_t)p*N*1024 + base) = *(uint4*)o;
  }
}

// ================= phase helpers =================
// Block geometry: XCD xcc owns batch rows [xcc*32, +32). rank in [0,32) -> cols
// [rank*32, +32) per gate. 4 waves: rf=w&1 (16-row half), cf=w>>1 (16-col half).
// MODE0 encoder: K=2048 = [x_t | h3] vs [Wih | Whh], length-mask.
// MODE1 decode:  K=2048 = [cur3 | h3] vs [Wih | Whh].
// MODE2 decode:  K=1024 = h3 vs Whh + f32 W_ih column gather (one-hot cur).
template<int PL, int MODE>
__device__ __forceinline__ void gates_do(
    const ushort* __restrict__ A0, const ushort* __restrict__ A1,
    const float* __restrict__ xsrc,
    const ushort* __restrict__ Wih, const ushort* __restrict__ Whh,
    const float* __restrict__ Wihf, const int* __restrict__ pred,
    int t, const int* len4,
    float* creg, ushort* __restrict__ h3new, LdsAS& As,
    int b0, int rank, int rf, int cf, int fr, int q, int arow, int a4,
    float bs0, float bs1, float bs2, float bs3)
{
  constexpr int KT = (MODE==2) ? 32 : 64;
  f32x4 acc[4] = {};

#define LOADSA(dst, kc) { \
  if (MODE==0 && (kc) < 32){ \
    float4 xv = *(const float4*)(xsrc + (size_t)(b0+arow)*(TENC*HID) + (size_t)t*HID + (kc)*32 + a4); \
    float vv[4] = {xv.x, xv.y, xv.z, xv.w}; \
    _Pragma("unroll") for (int p=0;p<PL;p++){ \
      ushort o[4]; \
      _Pragma("unroll") for (int e=0;e<4;e++){ ushort pp = bf16rn(vv[e]); vv[e] -= bf16tof(pp); o[e] = pp; } \
      dst[p] = *(uint2*)o; \
    } \
  } else { \
    const ushort* asel = (MODE==1 && (kc) < 32) ? A0 : A1; \
    int kl = (kc) & 31; \
    _Pragma("unroll") for (int p=0;p<PL;p++) \
      dst[p] = *(const uint2*)(asel + (size_t)p*H3PL + (size_t)(b0+arow)*1024 + kl*32 + a4); \
  } }

#define LOADB(dst, kc) { \
  const ushort* wsel = ((MODE!=2) && (kc) < 32) ? Wih : Whh; \
  int kl = (kc) & 31; \
  _Pragma("unroll") for (int p=0;p<PL;p++) \
  _Pragma("unroll") for (int g=0; g<4; g++) \
    dst[p][g] = *(const short8*)(wsel + (size_t)p*WPLE + ((size_t)(g*64 + rank*2 + cf)*128 + kl*4 + q)*128 + fr*8); }

#define STAGE(buf, sv) { _Pragma("unroll") for (int p=0;p<PL;p++) *(uint2*)&As[buf][p][arow][a4] = sv[p]; }

#define READA(af, buf) { _Pragma("unroll") for (int p=0;p<PL;p++) af[p] = *(const short8*)&As[buf][p][rf*16 + fr][q*8]; }

#define DOMFMA(af, bf) { _Pragma("unroll") for (int g=0; g<4; g++){ \
  if constexpr (PL==3){ \
    acc[g] = MFMA_B(af[2], bf[0][g], acc[g], 0,0,0); \
    acc[g] = MFMA_B(af[1], bf[1][g], acc[g], 0,0,0); \
    acc[g] = MFMA_B(af[0], bf[2][g], acc[g], 0,0,0); \
    acc[g] = MFMA_B(af[1], bf[0][g], acc[g], 0,0,0); \
    acc[g] = MFMA_B(af[0], bf[1][g], acc[g], 0,0,0); \
    acc[g] = MFMA_B(af[0], bf[0][g], acc[g], 0,0,0); \
  } else { \
    acc[g] = MFMA_B(af[0], bf[0][g], acc[g], 0,0,0); \
  } } }

  uint2 svA[PL];
  short8 bcur[PL][4], bnxt[PL][4], af[PL];
  LOADSA(svA, 0); LOADB(bcur, 0);
  for (int kc = 0; kc < KT; kc += 2){
    STAGE(0, svA);
    __syncthreads();
    LOADSA(svA, kc+1);
    LOADB(bnxt, kc+1);
    READA(af, 0);
    DOMFMA(af, bcur);
    STAGE(1, svA);
    __syncthreads();
    if (kc+2 < KT){ LOADSA(svA, kc+2); LOADB(bcur, kc+2); }
    READA(af, 1);
    DOMFMA(af, bnxt);
  }
#undef LOADSA
#undef LOADB
#undef STAGE
#undef READA
#undef DOMFMA

  int col = rank*32 + cf*16 + fr;
  #pragma unroll
  for (int r=0;r<4;r++){
    int b = b0 + rf*16 + q*4 + r;
    size_t cidx = (size_t)b*1024 + col;
    if (MODE==0 && t >= len4[r]){
      #pragma unroll
      for (int p=0;p<PL;p++) h3new[p*H3PL + cidx] = A1[p*H3PL + cidx];   // keep old h,c
      continue;
    }
    float gi = acc[0][r], gf = acc[1][r], gg2 = acc[2][r], go = acc[3][r];
    if (MODE==2){
      int pp = pred[b];
      gi  += Wihf[((size_t)(col       ))*HID + pp];
      gf  += Wihf[((size_t)(col + 1024))*HID + pp];
      gg2 += Wihf[((size_t)(col + 2048))*HID + pp];
      go  += Wihf[((size_t)(col + 3072))*HID + pp];
    }
    gi += bs0; gf += bs1; gg2 += bs2; go += bs3;
    float cn = sigm(gf)*creg[r] + sigm(gi)*tanhf(gg2);
    float hn = sigm(go)*tanhf(cn);
    creg[r] = cn;
    float v = hn;
    #pragma unroll
    for (int p=0;p<PL;p++){ ushort pp = bf16rn(v); v -= bf16tof(pp); h3new[p*H3PL + cidx] = pp; }
  }
}

// FC: logits rows [b0,b0+32) x cols [rank*32,+32) = h3 · wfc^T (K=1024)
template<int PL>
__device__ __forceinline__ void fc_do(
    const ushort* __restrict__ h3, const ushort* __restrict__ wfc,
    float* __restrict__ logits, int b0, int rank, int rf, int cf, int fr, int q)
{
  const ushort* ap = h3  + (size_t)(b0 + rf*16 + fr)*1024 + q*8;
  const ushort* bp = wfc + ((size_t)(rank*2 + cf)*128 + q)*128 + fr*8;
  f32x4 acc = {};
  short8 a0[PL], b0v[PL], a1[PL], b1v[PL];
  #pragma unroll
  for (int p=0;p<PL;p++){ a0[p] = *(const short8*)(ap + (size_t)p*H3PL); b0v[p] = *(const short8*)(bp + (size_t)p*VPLE); }
  for (int kc = 0; kc < 32; kc++){
    if (kc < 31){
      #pragma unroll
      for (int p=0;p<PL;p++){
        a1[p]  = *(const short8*)(ap + (size_t)p*H3PL + (kc+1)*32);
        b1v[p] = *(const short8*)(bp + (size_t)p*VPLE + (size_t)(kc+1)*4*128);
      }
    }
    if constexpr (PL==3){
      acc = MFMA_B(a0[2], b0v[0], acc, 0,0,0);
      acc = MFMA_B(a0[1], b0v[1], acc, 0,0,0);
      acc = MFMA_B(a0[0], b0v[2], acc, 0,0,0);
      acc = MFMA_B(a0[1], b0v[0], acc, 0,0,0);
      acc = MFMA_B(a0[0], b0v[1], acc, 0,0,0);
      acc = MFMA_B(a0[0], b0v[0], acc, 0,0,0);
    } else {
      acc = MFMA_B(a0[0], b0v[0], acc, 0,0,0);
    }
    #pragma unroll
    for (int p=0;p<PL;p++){ a0[p] = a1[p]; b0v[p] = b1v[p]; }
  }
  #pragma unroll
  for (int r=0;r<4;r++)
    logits[(size_t)(b0 + rf*16 + q*4 + r)*1024 + rank*32 + cf*16 + fr] = acc[r];
}

// decide: one block per batch b; state in registers
__device__ __forceinline__ void decide_do(
    const float* __restrict__ logits, const float* __restrict__ b_fc, int t, int b,
    int* anyA, int* pred, float* __restrict__ out, ushort* __restrict__ cur3,
    int& isth, int& tsteps, int& osteps,
    float* s_red, int* s_idx, int* s_misc, int tid)
{
  if (tid==0) s_misc[0] = __hip_atomic_load(&anyA[t], __ATOMIC_RELAXED, __HIP_MEMORY_SCOPE_AGENT);
  uint32_t fk0, fk1; tf2x32(0u, 42u, 0u, (uint32_t)t, fk0, fk1);
  float lg[4];
  float zb = -3.4e38f; int ib = 0;
  #pragma unroll
  for (int q2=0;q2<4;q2++){
    int v = tid + (q2<<8);
    uint32_t bits = jax_bits(fk0, fk1, (uint32_t)(b*VOCAB + v));
    float f = __uint_as_float((bits>>9) | 0x3F800000u) - 1.0f;
    const float TINY = 1.17549435e-38f;
    float u = fmaxf(TINY, f + TINY);
    float g = -logf(-logf(u));
    float l = logits[(size_t)b*VOCAB + v] + b_fc[v];
    lg[q2] = l;
    float zz = l + g;
    if (zz > zb){ zb = zz; ib = v; }
  }
  s_red[tid] = zb; s_idx[tid] = ib;
  __syncthreads();
  for (int s2=128;s2>0;s2>>=1){
    if (tid < s2){
      float om = s_red[tid+s2]; int oi = s_idx[tid+s2];
      if (om > s_red[tid] || (om==s_red[tid] && oi < s_idx[tid])){ s_red[tid]=om; s_idx[tid]=oi; }
    }
    __syncthreads();
  }
  int predv = s_idx[0];
  int anyv  = s_misc[0];
  int outp = (!isth && osteps < NOUT) ? 1 : 0;
  int si = osteps < (NOUT-1) ? osteps : (NOUT-1);
  int nts = tsteps + (isth ? 1 : 0);
  int jf = (isth && ((predv==STOPCLS) || (nts >= MAXTHINK))) ? 1 : 0;
  int isnew = (isth && !jf) ? 1 : 0;
  if (tid==0){
    pred[b] = predv;
    if (isnew) __hip_atomic_fetch_or(&anyA[t+1], 1, __ATOMIC_RELAXED, __HIP_MEMORY_SCOPE_AGENT);
    if (t == TDEC-1) out[(size_t)BATCH*NOUT*(VOCAB-1) + b] = (float)nts;
  }
  osteps += outp; tsteps = nts; isth = isnew;
  #pragma unroll
  for (int q2=0;q2<4;q2++){
    int v = tid + (q2<<8);
    float l = lg[q2];
    float cv = anyv ? l : (v==predv ? 1.0f : 0.0f);
    if (t < MAXTHINK){
      float t2 = cv;
      #pragma unroll
      for (int p=0;p<3;p++){ ushort pp = bf16rn(t2); t2 -= bf16tof(pp); cur3[p*H3PL + b*1024 + v] = pp; }
    }
    if (outp && v < (VOCAB-1))
      out[((size_t)b*NOUT + si)*(VOCAB-1) + v] = l;
  }
}

// ================= persistent kernel =================
struct KP {
  const float *x, *W_ih, *b_fc, *bsum;
  const int *lengths;
  float *logits, *out;
  ushort *h3a, *h3b, *cur3, *wih3, *whh3, *wfc3;
  int *ints;
  int guard;
};

__global__ __launch_bounds__(256, 1) void persist(KP P)
{
  __shared__ __align__(16) LdsAS As;
  __shared__ float s_red[256];
  __shared__ int s_idx[256];
  __shared__ int s_misc[16];
  __shared__ char lds_pad[32768];          // + 40KB dynamic at launch -> 1 block/CU
  if (P.guard) ((volatile char*)lds_pad)[0] = 1;

  int tid = threadIdx.x;
  int xcc; asm("s_getreg_b32 %0, hwreg(HW_REG_XCC_ID)" : "=s"(xcc));
  xcc &= 7;
  if (tid == 0)
    s_misc[8] = __hip_atomic_fetch_add(&P.ints[I_CLAIM + xcc], 1, __ATOMIC_RELAXED, __HIP_MEMORY_SCOPE_AGENT);
  __syncthreads();
  int rank  = s_misc[8] & 31;              // 32 blocks per XCD, guaranteed by 1-block/CU
  int rk256 = xcc*32 + rank;
  int b0    = xcc*32;                       // this XCD's batch slice

  int lane = tid & 63, w = tid >> 6;
  int rf = w & 1, cf = w >> 1;
  int fr = lane & 15, q = lane >> 4;
  int arow = tid >> 3, a4 = (tid & 7) << 2;
  int col = rank*32 + cf*16 + fr;
  float bs0 = P.bsum[col], bs1 = P.bsum[col+1024], bs2 = P.bsum[col+2048], bs3 = P.bsum[col+3072];
  int len4[4];
  #pragma unroll
  for (int r=0;r<4;r++) len4[r] = P.lengths[b0 + rf*16 + q*4 + r];
  float creg[4] = {0.f,0.f,0.f,0.f};

  int* flags = P.ints + I_FLAGS;
  int* gen   = P.ints + I_GEN;
  int* anyA  = P.ints + I_ANY;
  int* pred  = P.ints + I_PRED;
  int epoch = 0;
  ushort* h3[2] = { P.h3a, P.h3b };
  int hc = 0;
  int isth = 1, tsteps = 0, osteps = 0;    // decide state for batch rk256 (in regs)

#define GBAR() gbar(flags, gen, ++epoch, rk256, tid)

  // ---- encoder: 128 steps, one phase each (x|h fused K=2048) ----
  for (int t = 0; t < TENC; ++t){
    gates_do<3,0>(nullptr, h3[hc], P.x, P.wih3, P.whh3, nullptr, nullptr,
                  t, len4, creg, h3[hc^1], As,
                  b0, rank, rf, cf, fr, q, arow, a4, bs0, bs1, bs2, bs3);
    hc ^= 1;
    GBAR();
  }

  // ---- decode: 141 steps x {gates, fc, decide} ----
  for (int t = 0; t < TDEC; ++t){
    if (t < MAXTHINK)
      gates_do<3,1>(P.cur3, h3[hc], nullptr, P.wih3, P.whh3, nullptr, nullptr,
                    t, len4, creg, h3[hc^1], As,
                    b0, rank, rf, cf, fr, q, arow, a4, bs0, bs1, bs2, bs3);
    else if (t == MAXTHINK)   // cur is still LOGITS here (any was true at t=15)
      gates_do<1,1>(P.cur3, h3[hc], nullptr, P.wih3, P.whh3, nullptr, nullptr,
                    t, len4, creg, h3[hc^1], As,
                    b0, rank, rf, cf, fr, q, arow, a4, bs0, bs1, bs2, bs3);
    else                      // t>=17: cur exactly one-hot -> f32 W_ih column gather
      gates_do<1,2>(nullptr, h3[hc], nullptr, nullptr, P.whh3, P.W_ih, pred,
                    t, len4, creg, h3[hc^1], As,
                    b0, rank, rf, cf, fr, q, arow, a4, bs0, bs1, bs2, bs3);
    hc ^= 1;
    GBAR();
    if (t < MAXTHINK) fc_do<3>(h3[hc], P.wfc3, P.logits, b0, rank, rf, cf, fr, q);
    else              fc_do<1>(h3[hc], P.wfc3, P.logits, b0, rank, rf, cf, fr, q);
    GBAR();
    decide_do(P.logits, P.b_fc, t, rk256, anyA, pred, P.out, P.cur3,
              isth, tsteps, osteps, s_red, s_idx, s_misc, tid);
    GBAR();
  }
#undef GBAR
}

// ---------------- host ----------------
extern "C" void kernel_launch(void* const* d_in, const int* in_sizes, int n_in,
                              void* d_out, int out_size, void* d_ws, size_t ws_size,
                              hipStream_t stream)
{
  const float* x    = (const float*)d_in[0];
  const float* W_ih = (const float*)d_in[1];
  const float* W_hh = (const float*)d_in[2];
  const float* b_ih = (const float*)d_in[3];
  const float* b_hh = (const float*)d_in[4];
  const float* W_fc = (const float*)d_in[5];
  const float* b_fc = (const float*)d_in[6];
  const int*   lengths = (const int*)d_in[7];
  float* out = (float*)d_out;
  char* W = (char*)d_ws;

  constexpr size_t OF_BSUM = 0;
  constexpr size_t OF_LG   = OF_BSUM + 16384;
  constexpr size_t OF_H3A  = OF_LG   + 1048576;
  constexpr size_t OF_H3B  = OF_H3A  + 1572864;
  constexpr size_t OF_CUR3 = OF_H3B  + 1572864;
  constexpr size_t OF_WIH  = OF_CUR3 + 1572864;
  constexpr size_t OF_WHH  = OF_WIH  + (size_t)3*NGATE*1024*2;
  constexpr size_t OF_WFC  = OF_WHH  + (size_t)3*NGATE*1024*2;
  constexpr size_t OF_INTS = OF_WFC  + (size_t)3*VOCAB*1024*2;

  float* bsum   = (float*)(W + OF_BSUM);
  float* logits = (float*)(W + OF_LG);
  ushort* h3a   = (ushort*)(W + OF_H3A);
  ushort* h3b   = (ushort*)(W + OF_H3B);
  ushort* cur3  = (ushort*)(W + OF_CUR3);
  ushort* wih3  = (ushort*)(W + OF_WIH);
  ushort* whh3  = (ushort*)(W + OF_WHH);
  ushort* wfc3  = (ushort*)(W + OF_WFC);
  int* ints = (int*)(W + OF_INTS);

  splitw_kernel<<<NGATE/2, 256, 0, stream>>>(W_ih, wih3, NGATE);
  splitw_kernel<<<NGATE/2, 256, 0, stream>>>(W_hh, whh3, NGATE);
  splitw_kernel<<<VOCAB/2, 256, 0, stream>>>(W_fc, wfc3, VOCAB);
  prep_kernel<<<1024, 256, 0, stream>>>(b_ih, b_hh, x, lengths, bsum, ints, h3a, cur3);

  KP P;
  P.x = x; P.W_ih = W_ih; P.b_fc = b_fc; P.bsum = bsum; P.lengths = lengths;
  P.logits = logits; P.out = out;
  P.h3a = h3a; P.h3b = h3b; P.cur3 = cur3;
  P.wih3 = wih3; P.whh3 = whh3; P.wfc3 = wfc3;
  P.ints = ints;
  P.guard = 0;

  persist<<<dim3(256), dim3(256), 40960, stream>>>(P);
}